// Round 4
// baseline (2363.169 us; speedup 1.0000x reference)
//
#include <hip/hip_runtime.h>
#include <hip/hip_bf16.h>

#define N_NODESC 100000
#define N_EDGESC 3200000
#define FDIM 512
#define MPAD 100096   // 782 * 128
#define WSHIFT 11     // window = 2048 cols = 2MB of support
#define NBUCK 64      // buckets per row (pow2); used 0..48
#define NW 49
#define NOFF (N_NODESC * NBUCK)   // 6.4M counters
#define RPW 24        // rows per wave in spmm (bf16 acc: 96 VGPR)

typedef __attribute__((ext_vector_type(4))) float f32x4;
typedef __attribute__((ext_vector_type(8))) __bf16 bf16x8;
typedef __attribute__((ext_vector_type(4))) __bf16 bf16x4;
typedef unsigned long long u64;

__device__ __forceinline__ void gload_lds16(const void* g, void* l) {
  __builtin_amdgcn_global_load_lds(
      (const __attribute__((address_space(1))) unsigned int*)g,
      (__attribute__((address_space(3))) unsigned int*)l, 16, 0, 0);
}

// ---- weight: f32 [K][N] -> bf16 transposed wT [N][K] ----
__global__ void k_convert_wT(const float* __restrict__ w, __bf16* __restrict__ wT) {
  int i = blockIdx.x * 256 + threadIdx.x;
  if (i >= FDIM * FDIM) return;
  int k = i >> 9, n = i & (FDIM - 1);
  wT[n * FDIM + k] = (__bf16)w[i];
}

// ---- CSR build with per-row column-window buckets ----
__global__ void k_hist(const int* __restrict__ rows, const int* __restrict__ cols,
                       int* __restrict__ off8) {
  int e = blockIdx.x * 256 + threadIdx.x;
  if (e >= N_EDGESC) return;
  atomicAdd(&off8[rows[e] * NBUCK + (cols[e] >> WSHIFT)], 1);
}

// exclusive scan over off8[0..NOFF): 8192 elems per block
__global__ __launch_bounds__(1024) void k_scan1(int* __restrict__ d, int* __restrict__ bsum) {
  __shared__ int s[1024];
  const int t = threadIdx.x;
  const long base = (long)blockIdx.x * 8192 + (long)t * 8;
  int v[8];
  int sum = 0;
  #pragma unroll
  for (int k = 0; k < 8; ++k) {
    v[k] = (base + k < NOFF) ? d[base + k] : 0;
    sum += v[k];
  }
  s[t] = sum;
  __syncthreads();
  for (int dl = 1; dl < 1024; dl <<= 1) {
    int a = s[t];
    int b = (t >= dl) ? s[t - dl] : 0;
    __syncthreads();
    s[t] = a + b;
    __syncthreads();
  }
  int excl = (t == 0) ? 0 : s[t - 1];
  #pragma unroll
  for (int k = 0; k < 8; ++k) {
    if (base + k < NOFF) d[base + k] = excl;
    excl += v[k];
  }
  if (t == 1023) bsum[blockIdx.x] = s[1023];
}

__global__ __launch_bounds__(1024) void k_scan2(int* __restrict__ bsum, int nb,
                                                int* __restrict__ d) {
  __shared__ int s[1024];
  const int t = threadIdx.x;
  s[t] = (t < nb) ? bsum[t] : 0;
  __syncthreads();
  for (int dl = 1; dl < 1024; dl <<= 1) {
    int a = s[t];
    int b = (t >= dl) ? s[t - dl] : 0;
    __syncthreads();
    s[t] = a + b;
    __syncthreads();
  }
  if (t < nb) bsum[t] = (t == 0) ? 0 : s[t - 1];
  if (t == 0) d[NOFF] = s[1023];
}

__global__ void k_scan3(int* __restrict__ d, const int* __restrict__ bsum,
                        int* __restrict__ cur) {
  long i = (long)blockIdx.x * 256 + threadIdx.x;
  if (i >= NOFF) return;
  const int v = d[i] + bsum[i >> 13];
  d[i] = v;
  cur[i] = v;
}

__global__ void k_scatter(const int* __restrict__ rows, const int* __restrict__ cols,
                          const float* __restrict__ vals, int* __restrict__ cur,
                          u64* __restrict__ edges) {
  int e = blockIdx.x * 256 + threadIdx.x;
  if (e >= N_EDGESC) return;
  const int c = cols[e];
  const int p = atomicAdd(&cur[rows[e] * NBUCK + (c >> WSHIFT)], 1);
  edges[p] = ((u64)__float_as_uint(vals[e]) << 32) | (unsigned)c;
}

// ---- GEMM: support[MPAD][512] (bf16) = x[.][512] (f32, converted on the fly) @ w ----
__global__ __launch_bounds__(256) void k_gemm(const float* __restrict__ x,
                                              const __bf16* __restrict__ wT,
                                              __bf16* __restrict__ support) {
  __shared__ __bf16 lA[2][128 * 32];
  __shared__ __bf16 lB[2][128 * 32];   // n-major: lB[n][k]
  const int tm = blockIdx.x >> 2;
  const int tn = blockIdx.x & 3;
  const int tid = threadIdx.x;
  const int wid = tid >> 6;
  const int lane = tid & 63;
  const int wm = wid >> 1;
  const int wn = wid & 1;

  const long rowA0 = (long)tm * 128;
  const int  ncol0 = tn * 128;

  const int srow  = lane >> 2;
  const int skoff = (lane & 3) * 8;

  // A reg-stage geometry: thread covers rows {i*32 + tid>>3}, k = (tid&7)*4
  const int arow = tid >> 3;
  const int ak   = (tid & 7) * 4;

  f32x4 acc[4][4];
  #pragma unroll
  for (int m = 0; m < 4; ++m)
    #pragma unroll
    for (int n = 0; n < 4; ++n)
      acc[m][n] = (f32x4){0.f, 0.f, 0.f, 0.f};

  float4 ar[4];
  auto loadA = [&](int kt) {
    const int k0 = kt * 32;
    #pragma unroll
    for (int i = 0; i < 4; ++i) {
      const long grow = rowA0 + i * 32 + arow;
      const long cl = (grow < N_NODESC) ? grow : (N_NODESC - 1);
      ar[i] = *(const float4*)(x + cl * FDIM + k0 + ak);
    }
  };
  auto writeA = [&](int buf) {
    #pragma unroll
    for (int i = 0; i < 4; ++i) {
      const int row = i * 32 + arow;
      const bool pad = (rowA0 + row) >= N_NODESC;
      bf16x4 o;
      o[0] = (__bf16)(pad ? 0.f : ar[i].x);
      o[1] = (__bf16)(pad ? 0.f : ar[i].y);
      o[2] = (__bf16)(pad ? 0.f : ar[i].z);
      o[3] = (__bf16)(pad ? 0.f : ar[i].w);
      *(bf16x4*)&lA[buf][row * 32 + ak] = o;
    }
  };
  auto stageB = [&](int buf, int kt) {
    const int k0 = kt * 32;
    #pragma unroll
    for (int it = 0; it < 2; ++it) {
      const int c = wid * 2 + it;               // chunk 0..7 (wave-uniform)
      const __bf16* gB = wT + (long)(ncol0 + c * 16 + srow) * FDIM + k0 + skoff;
      gload_lds16(gB, &lB[buf][c * 512]);
    }
  };

  loadA(0);
  stageB(0, 0);
  writeA(0);
  __syncthreads();

  const int frow = lane & 15;
  const int fk   = (lane >> 4) * 8;

  for (int kt = 0; kt < 16; ++kt) {
    const int buf = kt & 1;
    bf16x8 a[4], b[4];
    #pragma unroll
    for (int m = 0; m < 4; ++m)
      a[m] = *(const bf16x8*)&lA[buf][(wm * 64 + m * 16 + frow) * 32 + fk];
    #pragma unroll
    for (int n = 0; n < 4; ++n)
      b[n] = *(const bf16x8*)&lB[buf][(wn * 64 + n * 16 + frow) * 32 + fk];
    if (kt + 1 < 16) {
      loadA(kt + 1);
      stageB(buf ^ 1, kt + 1);
    }
    #pragma unroll
    for (int m = 0; m < 4; ++m)
      #pragma unroll
      for (int n = 0; n < 4; ++n)
        acc[m][n] = __builtin_amdgcn_mfma_f32_16x16x32_bf16(a[m], b[n], acc[m][n], 0, 0, 0);
    if (kt + 1 < 16) writeA(buf ^ 1);
    __syncthreads();
  }

  // C/D layout (m89-verified): col = lane&15, row = (lane>>4)*4 + i
  const long crow0 = (long)tm * 128 + wm * 64 + (lane >> 4) * 4;
  const int  ccol0 = tn * 128 + wn * 64 + frow;
  #pragma unroll
  for (int m = 0; m < 4; ++m)
    #pragma unroll
    for (int n = 0; n < 4; ++n)
      #pragma unroll
      for (int i = 0; i < 4; ++i)
        support[(crow0 + m * 16 + i) * (long)FDIM + ccol0 + n * 16] = (__bf16)acc[m][n][i];
}

// ---- SpMM: persistent-ish waves, 24 rows/wave (bf16 acc), lockstep window sweep ----
__global__ __launch_bounds__(256, 4) void k_spmm(const int* __restrict__ off8,
                                                 const u64* __restrict__ edges,
                                                 const __bf16* __restrict__ support,
                                                 float* __restrict__ out) {
  const int wglob = blockIdx.x * 4 + (threadIdx.x >> 6);
  const int lane = threadIdx.x & 63;
  const int r0 = wglob * RPW;
  const __bf16* sp = support + lane * 8;

  bf16x8 acc[RPW];
  #pragma unroll
  for (int i = 0; i < RPW; ++i)
    #pragma unroll
    for (int q = 0; q < 8; ++q) acc[i][q] = (__bf16)0.0f;

  for (int w = 0; w < NW; ++w) {
    #pragma unroll
    for (int i = 0; i < RPW; ++i) {
      const int r = r0 + i;
      if (r < N_NODESC) {
        const int jbase = (r << 6) + w;
        const int j0 = off8[jbase];
        const int j1 = off8[jbase + 1];
        for (int j = j0; j < j1; ++j) {
          const u64 e = edges[j];
          const bf16x8 s = *(const bf16x8*)(sp + (long)(unsigned)(e & 0xffffffffu) * FDIM);
          const float v = __uint_as_float((unsigned)(e >> 32));
          float t[8];
          #pragma unroll
          for (int q = 0; q < 8; ++q) t[q] = (float)acc[i][q] + v * (float)s[q];
          #pragma unroll
          for (int q = 0; q < 8; ++q) acc[i][q] = (__bf16)t[q];
        }
      }
    }
  }

  #pragma unroll
  for (int i = 0; i < RPW; ++i) {
    const int r = r0 + i;
    if (r < N_NODESC) {
      *(f32x4*)(out + (long)r * FDIM + lane * 8) =
          (f32x4){(float)acc[i][0], (float)acc[i][1], (float)acc[i][2], (float)acc[i][3]};
      *(f32x4*)(out + (long)r * FDIM + lane * 8 + 4) =
          (f32x4){(float)acc[i][4], (float)acc[i][5], (float)acc[i][6], (float)acc[i][7]};
    }
  }
}

extern "C" void kernel_launch(void* const* d_in, const int* in_sizes, int n_in,
                              void* d_out, int out_size, void* d_ws, size_t ws_size,
                              hipStream_t stream) {
  const float* x    = (const float*)d_in[0];
  const float* w    = (const float*)d_in[1];
  const int*   rows = (const int*)d_in[2];
  const int*   cols = (const int*)d_in[3];
  const float* vals = (const float*)d_in[4];
  float* out = (float*)d_out;

  char* ws = (char*)d_ws;
  size_t off = 0;
  auto alloc = [&](size_t bytes) {
    void* p = ws + off;
    off += (bytes + 255) & ~(size_t)255;
    return p;
  };
  __bf16* support = (__bf16*)alloc((size_t)MPAD * FDIM * 2);      // 102.5 MB
  __bf16* wT      = (__bf16*)alloc((size_t)FDIM * FDIM * 2);      // 0.5 MB
  int*    off8    = (int*)alloc((size_t)(NOFF + 1) * 4);          // 25.6 MB
  int*    cur     = (int*)alloc((size_t)NOFF * 4);                // 25.6 MB
  int*    bsum    = (int*)alloc(1024 * 4);
  u64*    edges   = (u64*)alloc((size_t)N_EDGESC * 8);            // 25.6 MB
  (void)ws_size;

  const int NB_SCAN = (NOFF + 8191) / 8192;   // 782

  hipMemsetAsync(off8, 0, (size_t)(NOFF + 1) * 4, stream);

  k_convert_wT<<<(FDIM * FDIM + 255) / 256, 256, 0, stream>>>(w, wT);
  k_hist<<<(N_EDGESC + 255) / 256, 256, 0, stream>>>(rows, cols, off8);
  k_scan1<<<NB_SCAN, 1024, 0, stream>>>(off8, bsum);
  k_scan2<<<1, 1024, 0, stream>>>(bsum, NB_SCAN, off8);
  k_scan3<<<(NOFF + 255) / 256, 256, 0, stream>>>(off8, bsum, cur);
  k_scatter<<<(N_EDGESC + 255) / 256, 256, 0, stream>>>(rows, cols, vals, cur, edges);
  k_gemm<<<(MPAD / 128) * 4, 256, 0, stream>>>(x, wT, support);
  const int SPMM_BLOCKS = (N_NODESC + RPW * 4 - 1) / (RPW * 4);   // 1042
  k_spmm<<<SPMM_BLOCKS, 256, 0, stream>>>(off8, edges, support, out);
}

// Round 5
// 1199.513 us; speedup vs baseline: 1.9701x; 1.9701x over previous
//
#include <hip/hip_runtime.h>
#include <hip/hip_bf16.h>

#define N_NODESC 100000
#define N_EDGESC 3200000
#define FDIM 512
#define MPAD 100096   // 782 * 128

typedef __attribute__((ext_vector_type(4))) float f32x4;
typedef __attribute__((ext_vector_type(8))) __bf16 bf16x8;
typedef __attribute__((ext_vector_type(4))) __bf16 bf16x4;
typedef unsigned long long u64;

__device__ __forceinline__ void gload_lds16(const void* g, void* l) {
  __builtin_amdgcn_global_load_lds(
      (const __attribute__((address_space(1))) unsigned int*)g,
      (__attribute__((address_space(3))) unsigned int*)l, 16, 0, 0);
}

// ---- weight: f32 [K][N] -> bf16 transposed wT [N][K] ----
__global__ void k_convert_wT(const float* __restrict__ w, __bf16* __restrict__ wT) {
  int i = blockIdx.x * 256 + threadIdx.x;
  if (i >= FDIM * FDIM) return;
  int k = i >> 9, n = i & (FDIM - 1);
  wT[n * FDIM + k] = (__bf16)w[i];
}

// ---- CSR build (row-major only, no windows) ----
__global__ void k_hist(const int* __restrict__ rows, int* __restrict__ row_off) {
  int e = blockIdx.x * 256 + threadIdx.x;
  if (e >= N_EDGESC) return;
  atomicAdd(&row_off[rows[e] + 1], 1);
}

// single-block scan over 100K counts; also emits row_cur (= row starts)
__global__ __launch_bounds__(1024) void k_scan(int* __restrict__ row_off,
                                               int* __restrict__ row_cur) {
  __shared__ int part[1024];
  const int t = threadIdx.x;
  const int CH = (N_NODESC + 1023) / 1024;  // 98
  const int lo = t * CH;
  const int hi = min(lo + CH, N_NODESC);
  int s = 0;
  for (int i = lo; i < hi; ++i) s += row_off[1 + i];
  part[t] = s;
  __syncthreads();
  for (int d = 1; d < 1024; d <<= 1) {
    int v = part[t];
    int u = (t >= d) ? part[t - d] : 0;
    __syncthreads();
    part[t] = v + u;
    __syncthreads();
  }
  int run = (t == 0) ? 0 : part[t - 1];
  for (int i = lo; i < hi; ++i) {
    row_cur[i] = run;
    run += row_off[1 + i];
    row_off[1 + i] = run;
  }
  if (t == 0) row_off[0] = 0;
}

__global__ void k_scatter(const int* __restrict__ rows, const int* __restrict__ cols,
                          const float* __restrict__ vals, int* __restrict__ row_cur,
                          u64* __restrict__ edges) {
  int e = blockIdx.x * 256 + threadIdx.x;
  if (e >= N_EDGESC) return;
  const int p = atomicAdd(&row_cur[rows[e]], 1);
  edges[p] = ((u64)__float_as_uint(vals[e]) << 32) | (unsigned)cols[e];
}

// ---- GEMM: support[MPAD][512] (bf16) = x (f32, converted on the fly) @ w ----
__global__ __launch_bounds__(256) void k_gemm(const float* __restrict__ x,
                                              const __bf16* __restrict__ wT,
                                              __bf16* __restrict__ support) {
  __shared__ __bf16 lA[2][128 * 32];
  __shared__ __bf16 lB[2][128 * 32];   // n-major: lB[n][k]
  const int tm = blockIdx.x >> 2;
  const int tn = blockIdx.x & 3;
  const int tid = threadIdx.x;
  const int wid = tid >> 6;
  const int lane = tid & 63;
  const int wm = wid >> 1;
  const int wn = wid & 1;

  const long rowA0 = (long)tm * 128;
  const int  ncol0 = tn * 128;

  const int srow  = lane >> 2;
  const int skoff = (lane & 3) * 8;

  const int arow = tid >> 3;        // 0..31
  const int ak   = (tid & 7) * 4;   // 0..28

  f32x4 acc[4][4];
  #pragma unroll
  for (int m = 0; m < 4; ++m)
    #pragma unroll
    for (int n = 0; n < 4; ++n)
      acc[m][n] = (f32x4){0.f, 0.f, 0.f, 0.f};

  float4 ar[4];
  auto loadA = [&](int kt) {
    const int k0 = kt * 32;
    #pragma unroll
    for (int i = 0; i < 4; ++i) {
      const long grow = rowA0 + i * 32 + arow;
      const long cl = (grow < N_NODESC) ? grow : (N_NODESC - 1);
      ar[i] = *(const float4*)(x + cl * FDIM + k0 + ak);
    }
  };
  auto writeA = [&](int buf) {
    #pragma unroll
    for (int i = 0; i < 4; ++i) {
      const int row = i * 32 + arow;
      const bool pad = (rowA0 + row) >= N_NODESC;
      bf16x4 o;
      o[0] = (__bf16)(pad ? 0.f : ar[i].x);
      o[1] = (__bf16)(pad ? 0.f : ar[i].y);
      o[2] = (__bf16)(pad ? 0.f : ar[i].z);
      o[3] = (__bf16)(pad ? 0.f : ar[i].w);
      *(bf16x4*)&lA[buf][row * 32 + ak] = o;
    }
  };
  auto stageB = [&](int buf, int kt) {
    const int k0 = kt * 32;
    #pragma unroll
    for (int it = 0; it < 2; ++it) {
      const int c = wid * 2 + it;
      const __bf16* gB = wT + (long)(ncol0 + c * 16 + srow) * FDIM + k0 + skoff;
      gload_lds16(gB, &lB[buf][c * 512]);
    }
  };

  loadA(0);
  stageB(0, 0);
  writeA(0);
  __syncthreads();

  const int frow = lane & 15;
  const int fk   = (lane >> 4) * 8;

  for (int kt = 0; kt < 16; ++kt) {
    const int buf = kt & 1;
    bf16x8 a[4], b[4];
    #pragma unroll
    for (int m = 0; m < 4; ++m)
      a[m] = *(const bf16x8*)&lA[buf][(wm * 64 + m * 16 + frow) * 32 + fk];
    #pragma unroll
    for (int n = 0; n < 4; ++n)
      b[n] = *(const bf16x8*)&lB[buf][(wn * 64 + n * 16 + frow) * 32 + fk];
    if (kt + 1 < 16) {
      loadA(kt + 1);
      stageB(buf ^ 1, kt + 1);
    }
    #pragma unroll
    for (int m = 0; m < 4; ++m)
      #pragma unroll
      for (int n = 0; n < 4; ++n)
        acc[m][n] = __builtin_amdgcn_mfma_f32_16x16x32_bf16(a[m], b[n], acc[m][n], 0, 0, 0);
    if (kt + 1 < 16) writeA(buf ^ 1);
    __syncthreads();
  }

  // C/D layout (m89-verified): col = lane&15, row = (lane>>4)*4 + i
  const long crow0 = (long)tm * 128 + wm * 64 + (lane >> 4) * 4;
  const int  ccol0 = tn * 128 + wn * 64 + frow;
  #pragma unroll
  for (int m = 0; m < 4; ++m)
    #pragma unroll
    for (int n = 0; n < 4; ++n)
      #pragma unroll
      for (int i = 0; i < 4; ++i)
        support[(crow0 + m * 16 + i) * (long)FDIM + ccol0 + n * 16] = (__bf16)acc[m][n][i];
}

// ---- SpMM: one wave per row, f32 acc, 4-edge unroll (plain loads) ----
__global__ __launch_bounds__(256) void k_spmm(const int* __restrict__ row_off,
                                              const u64* __restrict__ edges,
                                              const __bf16* __restrict__ support,
                                              float* __restrict__ out) {
  const int r = blockIdx.x * 4 + (threadIdx.x >> 6);
  const int lane = threadIdx.x & 63;
  if (r >= N_NODESC) return;
  const int beg = row_off[r];
  const int end = row_off[r + 1];
  const __bf16* sp = support + lane * 8;

  float acc[8];
  #pragma unroll
  for (int i = 0; i < 8; ++i) acc[i] = 0.f;

  int j = beg;
  for (; j + 4 <= end; j += 4) {
    const u64 e0 = edges[j];
    const u64 e1 = edges[j + 1];
    const u64 e2 = edges[j + 2];
    const u64 e3 = edges[j + 3];
    const bf16x8 s0 = *(const bf16x8*)(sp + (long)(unsigned)(e0 & 0xffffffffu) * FDIM);
    const bf16x8 s1 = *(const bf16x8*)(sp + (long)(unsigned)(e1 & 0xffffffffu) * FDIM);
    const bf16x8 s2 = *(const bf16x8*)(sp + (long)(unsigned)(e2 & 0xffffffffu) * FDIM);
    const bf16x8 s3 = *(const bf16x8*)(sp + (long)(unsigned)(e3 & 0xffffffffu) * FDIM);
    const float v0 = __uint_as_float((unsigned)(e0 >> 32));
    const float v1 = __uint_as_float((unsigned)(e1 >> 32));
    const float v2 = __uint_as_float((unsigned)(e2 >> 32));
    const float v3 = __uint_as_float((unsigned)(e3 >> 32));
    #pragma unroll
    for (int i = 0; i < 8; ++i) acc[i] += v0 * (float)s0[i];
    #pragma unroll
    for (int i = 0; i < 8; ++i) acc[i] += v1 * (float)s1[i];
    #pragma unroll
    for (int i = 0; i < 8; ++i) acc[i] += v2 * (float)s2[i];
    #pragma unroll
    for (int i = 0; i < 8; ++i) acc[i] += v3 * (float)s3[i];
  }
  for (; j < end; ++j) {
    const u64 e = edges[j];
    const bf16x8 s = *(const bf16x8*)(sp + (long)(unsigned)(e & 0xffffffffu) * FDIM);
    const float v = __uint_as_float((unsigned)(e >> 32));
    #pragma unroll
    for (int i = 0; i < 8; ++i) acc[i] += v * (float)s[i];
  }

  *(float4*)(out + (long)r * FDIM + lane * 8) =
      make_float4(acc[0], acc[1], acc[2], acc[3]);
  *(float4*)(out + (long)r * FDIM + lane * 8 + 4) =
      make_float4(acc[4], acc[5], acc[6], acc[7]);
}

extern "C" void kernel_launch(void* const* d_in, const int* in_sizes, int n_in,
                              void* d_out, int out_size, void* d_ws, size_t ws_size,
                              hipStream_t stream) {
  const float* x    = (const float*)d_in[0];
  const float* w    = (const float*)d_in[1];
  const int*   rows = (const int*)d_in[2];
  const int*   cols = (const int*)d_in[3];
  const float* vals = (const float*)d_in[4];
  float* out = (float*)d_out;

  char* ws = (char*)d_ws;
  size_t off = 0;
  auto alloc = [&](size_t bytes) {
    void* p = ws + off;
    off += (bytes + 255) & ~(size_t)255;
    return p;
  };
  __bf16* support = (__bf16*)alloc((size_t)MPAD * FDIM * 2);      // 102.5 MB
  __bf16* wT      = (__bf16*)alloc((size_t)FDIM * FDIM * 2);      // 0.5 MB
  int*    row_off = (int*)alloc((size_t)(N_NODESC + 1) * 4);
  int*    row_cur = (int*)alloc((size_t)(N_NODESC + 1) * 4);
  u64*    edges   = (u64*)alloc((size_t)N_EDGESC * 8);            // 25.6 MB
  (void)ws_size;

  hipMemsetAsync(row_off, 0, (size_t)(N_NODESC + 1) * 4, stream);

  k_convert_wT<<<(FDIM * FDIM + 255) / 256, 256, 0, stream>>>(w, wT);
  k_hist<<<(N_EDGESC + 255) / 256, 256, 0, stream>>>(rows, row_off);
  k_scan<<<1, 1024, 0, stream>>>(row_off, row_cur);
  k_scatter<<<(N_EDGESC + 255) / 256, 256, 0, stream>>>(rows, cols, vals, row_cur, edges);
  k_gemm<<<(MPAD / 128) * 4, 256, 0, stream>>>(x, wT, support);
  k_spmm<<<N_NODESC / 4, 256, 0, stream>>>(row_off, edges, support, out);
}